// Round 10
// baseline (190.321 us; speedup 1.0000x reference)
//
#include <hip/hip_runtime.h>
#include <hip/hip_bf16.h>

typedef __attribute__((ext_vector_type(4))) float f32x4;
typedef __attribute__((ext_vector_type(8))) short bf16x8;

#define NROWS 32768
#define DIM   2048
#define NEXP  64

__device__ __forceinline__ short f2bf(float f) {
    __hip_bfloat16 h = __float2bfloat16(f);   // RTNE
    short s;
    __builtin_memcpy(&s, &h, 2);
    return s;
}

// ---------------- Kernel A: expert prep -------------------------------------
__global__ __launch_bounds__(256) void prep_experts(
    const float* __restrict__ ek,
    short* __restrict__ ekbf,
    short* __restrict__ ekT,
    float* __restrict__ enorm)
{
    const int e = blockIdx.x;
    const int t = threadIdx.x;
    const float* row = ek + e * DIM;
    float ss = 0.f;
#pragma unroll
    for (int i = 0; i < 2; ++i) {
        const int c4 = t + i * 256;
        const float4 v = ((const float4*)row)[c4];
        ss += v.x * v.x + v.y * v.y + v.z * v.z + v.w * v.w;
        short4 b;
        b.x = f2bf(v.x); b.y = f2bf(v.y); b.z = f2bf(v.z); b.w = f2bf(v.w);
        *(short4*)(ekbf + e * DIM + c4 * 4) = b;
        const int d = c4 * 4;
        ekT[(d + 0) * NEXP + e] = b.x;
        ekT[(d + 1) * NEXP + e] = b.y;
        ekT[(d + 2) * NEXP + e] = b.z;
        ekT[(d + 3) * NEXP + e] = b.w;
    }
#pragma unroll
    for (int s = 1; s < 64; s <<= 1) ss += __shfl_xor(ss, s);
    __shared__ float red[4];
    if ((t & 63) == 0) red[t >> 6] = ss;
    __syncthreads();
    if (t == 0) enorm[e] = sqrtf(red[0] + red[1] + red[2] + red[3]);
}

// ---------------- Kernel 1: similarity (read-bound, linear-span staging) ----
// 16 rows/block, 2048 blocks, 4 waves. The block's 16 z-rows are a CONTIGUOUS
// 128 KiB span; wave w streams its contiguous 32 KiB quarter in pure linear
// order (1 KiB per load instruction, 8 in flight), converting to bf16 +
// accumulating sum-of-squares in flight, storing XOR-swizzled into LDS.
// Then one barrier and a lean MFMA loop (ds_read_b128 + L2 ek load + MFMA).
// No manual vmcnt (R9 lesson: counted vmcnt breaks when mixed with compiler
// loads). 2 blocks/CU; blocks desync so staging overlaps compute.
__global__ __launch_bounds__(256) void sim_kernel(
    const float* __restrict__ z,
    const short* __restrict__ ekbf,   // [64][2048] bf16
    const float* __restrict__ enorm,  // [64]
    float* __restrict__ out_sim)      // [32768][64]
{
    const int tid = threadIdx.x;
    const int w   = tid >> 6;
    const int l   = tid & 63;
    const int lr  = l & 15;
    const int lg  = l >> 4;
    const int base = blockIdx.x * 16;

    __shared__ __align__(16) short zbf[16][DIM];   // 64 KiB bf16, swizzled units
    __shared__ float znL[16];

    // ---- staging: wave w handles rows w*4 .. w*4+3 (each row = 8 KiB)
#pragma unroll 1
    for (int r = 0; r < 4; ++r) {
        const int row  = w * 4 + r;           // block-local row 0..15
        const int sw   = row & 7;             // swizzle key
        const size_t gbase = (size_t)(base + row) * DIM;
        float sa = 0.f, sb = 0.f;
#pragma unroll
        for (int jj = 0; jj < 8; ++jj) {
            const float4 v = *(const float4*)(z + gbase + jj * 256 + l * 4);
            sa = fmaf(v.x, v.x, sa); sb = fmaf(v.y, v.y, sb);
            sa = fmaf(v.z, v.z, sa); sb = fmaf(v.w, v.w, sb);
            ushort4 o;
            o.x = (unsigned short)f2bf(v.x);
            o.y = (unsigned short)f2bf(v.y);
            o.z = (unsigned short)f2bf(v.z);
            o.w = (unsigned short)f2bf(v.w);
            // granule g = jj*64 + l (4 bf16 = 8B); unit = g>>1; swizzled unit
            const int su = ((jj * 32 + (l >> 1)) ^ sw);
            *(ushort4*)((char*)&zbf[row][0] + su * 16 + (l & 1) * 8) = o;
        }
        float ssr = sa + sb;
#pragma unroll
        for (int d = 1; d < 64; d <<= 1) ssr += __shfl_xor(ssr, d);
        if (l == 0) znL[row] = sqrtf(ssr);
    }
    __syncthreads();

    // ---- compute: wave w owns experts w*16 .. w*16+15, all 16 rows
    const short* ebase = ekbf + (size_t)(w * 16 + lr) * DIM + lg * 8;
    const char*  zrow  = (const char*)&zbf[lr][0];
    const int    zsw   = lr & 7;
    f32x4 acc = f32x4{0.f, 0.f, 0.f, 0.f};

#pragma unroll 8
    for (int kk = 0; kk < 64; ++kk) {
        const bf16x8 bf = *(const bf16x8*)(ebase + kk * 32);
        const bf16x8 af = *(const bf16x8*)(zrow + (((kk * 4 + lg) ^ zsw) << 4));
        acc = __builtin_amdgcn_mfma_f32_16x16x32_bf16(af, bf, acc, 0, 0, 0);
    }

    // ---- write similarity. C layout: lane holds D[lg*4+j][lr].
    const float en = enorm[w * 16 + lr];
#pragma unroll
    for (int j = 0; j < 4; ++j) {
        const float znj = znL[lg * 4 + j];
        out_sim[(size_t)(base + lg * 4 + j) * NEXP + w * 16 + lr]
            = acc[j] / fmaxf(znj * en, 1e-8f);
    }
}

// ---------------- Kernel 2: softmax + weighted combine (R6 version) ---------
__global__ __launch_bounds__(256) void moe_kernel(
    const float* __restrict__ sim,    // [32768][64]
    const short* __restrict__ ekT,    // [2048][64] bf16
    float* __restrict__ out_wei)      // [32768][2048]
{
    const int tid = threadIdx.x;
    const int w   = tid >> 6;
    const int l   = tid & 63;
    const int lr  = l & 15;
    const int lg  = l >> 4;
    const int base = blockIdx.x * 32;
    const int col0 = blockIdx.y * 1024 + w * 256;

    __shared__ __align__(16) short WL[32][64];      // [row][e], 16B-unit XOR swizzled
    __shared__ __align__(16) float tbuf[4][32][68]; // per-wave transpose buffer

    {   // softmax: thread t -> row t>>3, experts (t&7)*8..+8
        const int r  = tid >> 3;
        const int cc = tid & 7;
        const float* sp = sim + (size_t)(base + r) * NEXP + cc * 8;
        const float4 v0 = *(const float4*)sp;
        const float4 v1 = *(const float4*)(sp + 4);
        float va[8] = {v0.x, v0.y, v0.z, v0.w, v1.x, v1.y, v1.z, v1.w};
        float m = va[0];
#pragma unroll
        for (int i = 1; i < 8; ++i) m = fmaxf(m, va[i]);
        m = fmaxf(m, __shfl_xor(m, 1));
        m = fmaxf(m, __shfl_xor(m, 2));
        m = fmaxf(m, __shfl_xor(m, 4));
        float sum = 0.f;
#pragma unroll
        for (int i = 0; i < 8; ++i) { va[i] = __expf(va[i] - m); sum += va[i]; }
        sum += __shfl_xor(sum, 1);
        sum += __shfl_xor(sum, 2);
        sum += __shfl_xor(sum, 4);
        const float inv = 1.0f / sum;
        bf16x8 wv;
#pragma unroll
        for (int i = 0; i < 8; ++i) wv[i] = f2bf(va[i] * inv);
        *(bf16x8*)&WL[r][(cc ^ (r & 7)) * 8] = wv;
    }
    __syncthreads();

    bf16x8 afr[2][2];
#pragma unroll
    for (int mt = 0; mt < 2; ++mt)
#pragma unroll
        for (int ks = 0; ks < 2; ++ks) {
            const int row = mt * 16 + lr;
            const int u   = (ks * 4 + lg) ^ (row & 7);
            afr[mt][ks] = *(const bf16x8*)&WL[row][u * 8];
        }

#pragma unroll 1
    for (int g = 0; g < 4; ++g) {
        f32x4 oacc[4][2];   // [nt2][mt]
#pragma unroll
        for (int nt2 = 0; nt2 < 4; ++nt2) {
            const int d0 = col0 + g * 64 + nt2 * 16;
            const short* bp = ekT + (size_t)(d0 + lr) * NEXP + lg * 8;
            const bf16x8 b0 = *(const bf16x8*)bp;
            const bf16x8 b1 = *(const bf16x8*)(bp + 32);
#pragma unroll
            for (int mt = 0; mt < 2; ++mt) {
                f32x4 o = f32x4{0.f, 0.f, 0.f, 0.f};
                o = __builtin_amdgcn_mfma_f32_16x16x32_bf16(afr[mt][0], b0, o, 0, 0, 0);
                o = __builtin_amdgcn_mfma_f32_16x16x32_bf16(afr[mt][1], b1, o, 0, 0, 0);
                oacc[nt2][mt] = o;
            }
        }
#pragma unroll
        for (int nt2 = 0; nt2 < 4; ++nt2)
#pragma unroll
            for (int mt = 0; mt < 2; ++mt)
#pragma unroll
                for (int j = 0; j < 4; ++j)
                    tbuf[w][mt * 16 + lg * 4 + j][nt2 * 16 + lr] = oacc[nt2][mt][j];
#pragma unroll
        for (int i = 0; i < 8; ++i) {
            const int row  = (l >> 4) + i * 4;
            const int unit = l & 15;
            const float4 t = *(const float4*)&tbuf[w][row][unit * 4];
            *(float4*)&out_wei[(size_t)(base + row) * DIM + col0 + g * 64 + unit * 4] = t;
        }
    }
}

// ---------------- launch -----------------------------------------------------
extern "C" void kernel_launch(void* const* d_in, const int* in_sizes, int n_in,
                              void* d_out, int out_size, void* d_ws, size_t ws_size,
                              hipStream_t stream) {
    const float* z  = (const float*)d_in[0];
    const float* ek = (const float*)d_in[1];
    float* out_sim = (float*)d_out;
    float* out_wei = out_sim + (size_t)NROWS * NEXP;

    short* ekbf  = (short*)d_ws;                 // 256 KiB
    short* ekT   = ekbf + NEXP * DIM;            // 256 KiB
    float* enorm = (float*)(ekT + DIM * NEXP);   // 256 B

    prep_experts<<<NEXP, 256, 0, stream>>>(ek, ekbf, ekT, enorm);
    sim_kernel<<<NROWS / 16, 256, 0, stream>>>(z, ekbf, enorm, out_sim);
    moe_kernel<<<dim3(NROWS / 32, 2), 256, 0, stream>>>(out_sim, ekT, out_wei);
}